// Round 12
// baseline (211.842 us; speedup 1.0000x reference)
//
#include <hip/hip_runtime.h>
#include <math.h>

#define BB   4
#define TT   4096
#define DIN  1024
#define DST  2048
#define MM   (BB*TT)     // 16384
#define CHK  32          // scan chunks per sequence
#define CLEN (TT/CHK)    // 128  (== GEMM BM, so M-tile bm <-> chunk identity)

typedef __bf16 bf16x8 __attribute__((ext_vector_type(8)));
typedef float  f32x16 __attribute__((ext_vector_type(16)));

__device__ __forceinline__ unsigned short f2bf(float f) {
    union { float f; unsigned u; } v; v.f = f;
    unsigned r = v.u + 0x7FFFu + ((v.u >> 16) & 1u);   // RNE
    return (unsigned short)(r >> 16);
}
__device__ __forceinline__ float bf2f(unsigned short h) {
    union { unsigned u; float f; } v; v.u = ((unsigned)h) << 16;
    return v.f;
}
__device__ __forceinline__ float sigm(float x) { return 1.f / (1.f + __expf(-x)); }

// ---------------------------------------------------------------------------
// fused fp32 -> bf16 conversion of u, W_in, W_out in ONE launch.
// ---------------------------------------------------------------------------
#define N_U4 (MM * DIN / 4)          // 4,194,304
#define N_W4 (DST * DIN / 4)         //   524,288

__global__ __launch_bounds__(256)
void cvt_all_kernel(const float* __restrict__ u,
                    const float* __restrict__ W_in,
                    const float* __restrict__ W_out,
                    unsigned short* __restrict__ uA,
                    unsigned short* __restrict__ wA,
                    unsigned short* __restrict__ wB)
{
    int i = blockIdx.x * 256 + threadIdx.x;
    const float* src; unsigned short* dst; int idx;
    if (i < N_U4)                { src = u;     dst = uA; idx = i; }
    else if (i < N_U4 + N_W4)    { src = W_in;  dst = wA; idx = i - N_U4; }
    else                         { src = W_out; dst = wB; idx = i - N_U4 - N_W4; }
    float4 f = reinterpret_cast<const float4*>(src)[idx];
    ushort4 o;
    o.x = f2bf(f.x); o.y = f2bf(f.y); o.z = f2bf(f.z); o.w = f2bf(f.w);
    reinterpret_cast<ushort4*>(dst)[idx] = o;
}

// ---------------------------------------------------------------------------
// m97-structure bf16 NT GEMM with 32x32x16 MFMA (higher FLOP/cyc, fewer LDS
// reads: 16 MFMA + 16 ds_read_b128 per wave per K-tile vs 32 + 24 for 16x16).
//   128x128 tile, BK=64, 4 waves (2x2), wave tile 64x64 = 2x2 frags of 32x32.
//   Single 32 KiB LDS buffer, 2-barrier loop, 3 blocks/CU.
//   XOR swizzle colgroup ^= (row&7) both-sides (stage source pre-swizzled).
// Layouts (gfx950):
//   A/B frag: row/col = lane&31, k = (lane>>5)*8 + j  (8 contiguous bf16)
//   C/D     : col = lane&31, row = (reg&3) + 8*(reg>>2) + 4*(lane>>5)
// FUSE=false (GEMM1): Obf = bf16(acc) + fused chunk-final fin[bm][s].
// FUSE=true  (GEMM2): Of  = acc + bf2f(Ubf)*Dv[col].
// ---------------------------------------------------------------------------
template<int K, int NB, bool FUSE>
__global__ __launch_bounds__(256, 3)
void gemm_m97(const unsigned short* __restrict__ A,
              const unsigned short* __restrict__ B,
              unsigned short* __restrict__ Obf,
              float* __restrict__ Of,
              const unsigned short* __restrict__ Ubf,
              const float* __restrict__ Dv,
              const float* __restrict__ logl,
              float* __restrict__ fin)
{
    constexpr int N  = NB * 128;
    constexpr int NT = K / 64;
    __shared__ __align__(16) unsigned short lds[16384];   // A 16KB + B 16KB

    // XCD-aware bijective swizzle (nwg % 8 == 0: 2048 / 1024 blocks)
    const int nwg = gridDim.x;
    const int bid = blockIdx.x;
    const int swz = (bid & 7) * (nwg >> 3) + (bid >> 3);
    const int bm = swz / NB, bn = swz % NB;

    const int tid  = threadIdx.x;
    const int lane = tid & 63;
    const int wid  = tid >> 6;          // 0..3
    const int wr   = wid >> 1;          // 0..1  (64-row band)
    const int wc   = wid & 1;           // 0..1  (64-col band)
    const int cl   = lane & 31;         // frag row/col
    const int hi   = lane >> 5;         // k-group half
    const int sw   = lane & 7;          // read-side swizzle key (row&7 == cl&7)

    // --- staging: linear LDS dest, pre-swizzled global source col ---
    const int srow = tid >> 3;                                  // 0..31
    const int scol = (((tid & 7) ^ (srow & 7)) << 3);           // swizzled col
    const unsigned short* Ag = A + (size_t)(bm * 128 + srow) * K + scol;
    const unsigned short* Bg = B + (size_t)(bn * 128 + srow) * K + scol;

    auto stage = [&](int t) {
        const size_t kof = (size_t)t * 64;
#pragma unroll
        for (int r = 0; r < 4; ++r)
            __builtin_amdgcn_global_load_lds(
                (const __attribute__((address_space(1))) void*)(Ag + kof + (size_t)(r * 32) * K),
                (__attribute__((address_space(3))) void*)(&lds[r * 2048 + tid * 8]),
                16, 0, 0);
#pragma unroll
        for (int r = 0; r < 4; ++r)
            __builtin_amdgcn_global_load_lds(
                (const __attribute__((address_space(1))) void*)(Bg + kof + (size_t)(r * 32) * K),
                (__attribute__((address_space(3))) void*)(&lds[8192 + r * 2048 + tid * 8]),
                16, 0, 0);
    };

    // --- frag read bases: row = wr*64 + mi*32 + cl (A), wc*64 + ni*32 + cl (B)
    const int aBase = (wr * 64 + cl) * 64;            // + mi*2048 + cg*8
    const int bBase = 8192 + (wc * 64 + cl) * 64;     // + ni*2048 + cg*8

    f32x16 acc[2][2];
#pragma unroll
    for (int mi = 0; mi < 2; ++mi)
#pragma unroll
        for (int ni = 0; ni < 2; ++ni)
#pragma unroll
            for (int r = 0; r < 16; ++r)
                acc[mi][ni][r] = 0.f;

    for (int t = 0; t < NT; ++t) {
        __syncthreads();            // all reads of buffer done (prev iter)
        stage(t);
        __syncthreads();            // compiler drains vmcnt before barrier

#pragma unroll
        for (int ks = 0; ks < 4; ++ks) {
            const int cg = ((ks * 2 + hi) ^ sw) << 3;   // swizzled k col-group
            bf16x8 af[2], bfv[2];
#pragma unroll
            for (int mi = 0; mi < 2; ++mi)
                af[mi] = *reinterpret_cast<const bf16x8*>(&lds[aBase + mi * 2048 + cg]);
#pragma unroll
            for (int ni = 0; ni < 2; ++ni)
                bfv[ni] = *reinterpret_cast<const bf16x8*>(&lds[bBase + ni * 2048 + cg]);
#pragma unroll
            for (int mi = 0; mi < 2; ++mi)
#pragma unroll
                for (int ni = 0; ni < 2; ++ni)
                    acc[mi][ni] = __builtin_amdgcn_mfma_f32_32x32x16_bf16(
                        af[mi], bfv[ni], acc[mi][ni], 0, 0, 0);
        }
    }

    // --- epilogue.  C/D: col = cl, row = (reg&3) + 8*(reg>>2) + 4*hi ---
    const int row0 = bm * 128 + wr * 64 + 4 * hi;     // + mi*32 + rr + 8*rq
    const int col0 = bn * 128 + wc * 64 + cl;         // + ni*32
    if (FUSE) {
#pragma unroll
        for (int ni = 0; ni < 2; ++ni) {
            const int col = col0 + ni * 32;
            const float d = Dv[col];
#pragma unroll
            for (int mi = 0; mi < 2; ++mi)
#pragma unroll
                for (int rq = 0; rq < 4; ++rq)
#pragma unroll
                    for (int rr = 0; rr < 4; ++rr) {
                        const size_t idx =
                            (size_t)(row0 + mi * 32 + rr + 8 * rq) * N + col;
                        Of[idx] = acc[mi][ni][rq * 4 + rr] + bf2f(Ubf[idx]) * d;
                    }
        }
    } else {
#pragma unroll
        for (int ni = 0; ni < 2; ++ni) {
            const int col = col0 + ni * 32;
#pragma unroll
            for (int mi = 0; mi < 2; ++mi)
#pragma unroll
                for (int rq = 0; rq < 4; ++rq)
#pragma unroll
                    for (int rr = 0; rr < 4; ++rr) {
                        const size_t idx =
                            (size_t)(row0 + mi * 32 + rr + 8 * rq) * N + col;
                        Obf[idx] = f2bf(acc[mi][ni][rq * 4 + rr]);
                    }
        }

        // ---- fused scan1: chunk-final fin[bm][s] from fp32 acc ----
        // row_local = wr*64 + mi*32 + 4*hi + rr + 8*rq
        // weight    = lam^(127-row_local) * (1-lam)
        float p[2];
#pragma unroll
        for (int ni = 0; ni < 2; ++ni) {
            const int col = bn * 128 + wc * 64 + ni * 32 + cl;
            const float lam = sigm(logl[col]);
            const float l2  = log2f(lam);
            const float e0  = (float)(127 - wr * 64 - 4 * hi);
            const float w0  = exp2f(e0 * l2) * (1.f - lam);
            const float li  = 1.f / lam;
            const float li2 = li * li,  li4 = li2 * li2;
            const float li8 = li4 * li4, li16 = li8 * li8, li32 = li16 * li16;
            float s = 0.f;
#pragma unroll
            for (int mi = 0; mi < 2; ++mi) {
                float wq = mi ? (w0 * li32) : w0;
#pragma unroll
                for (int rq = 0; rq < 4; ++rq) {
                    float w = wq;
#pragma unroll
                    for (int rr = 0; rr < 4; ++rr) {
                        s = fmaf(w, acc[mi][ni][rq * 4 + rr], s);
                        w *= li;
                    }
                    wq *= li8;
                }
            }
            p[ni] = s;
        }
        // combine hi halves (lane ^ 32 holds same col, rows +4 offset folded in w0)
#pragma unroll
        for (int ni = 0; ni < 2; ++ni)
            p[ni] += __shfl_xor(p[ni], 32, 64);
        __syncthreads();                        // LDS reuse safe
        float* part = reinterpret_cast<float*>(lds);   // [2][128]
        if (hi == 0) {
#pragma unroll
            for (int ni = 0; ni < 2; ++ni)
                part[wr * 128 + wc * 64 + ni * 32 + cl] = p[ni];
        }
        __syncthreads();
        if (tid < 128)
            fin[(size_t)bm * DST + bn * 128 + tid] = part[tid] + part[128 + tid];
    }
}

// ---------------------------------------------------------------------------
// scan3 (with inlined carry fold): for chunk c, carry = Horner over F[0..c-1],
// then x_t = lam*x_{t-1} + (1-lam)*up_t in place (bf16).
// ---------------------------------------------------------------------------
__global__ __launch_bounds__(256)
void scan3_kernel(unsigned short* __restrict__ up,
                  const float* __restrict__ logl,
                  const float* __restrict__ fin)
{
    const int gid = blockIdx.x * 256 + threadIdx.x;
    const int sp  = gid & (DST / 2 - 1);
    const int bc  = gid >> 10;                         // b*CHK + c
    const int c   = bc & (CHK - 1), b = bc >> 5;
    const int s0  = sp * 2;
    const float lam0 = sigm(logl[s0]),  lam1 = sigm(logl[s0 + 1]);
    const float o0 = 1.f - lam0, o1 = 1.f - lam1;
    float lamL0 = lam0, lamL1 = lam1;
#pragma unroll
    for (int i = 0; i < 7; ++i) { lamL0 *= lamL0; lamL1 *= lamL1; }   // lam^128

    // carry_in = sum_{c'<c} lamL^(c-1-c') * F[c']   (Horner, ascending c')
    float x0 = 0.f, x1 = 0.f;
    for (int cc = 0; cc < c; ++cc) {
        const float2 F = reinterpret_cast<const float2*>(
            fin + (size_t)(b * CHK + cc) * DST + s0)[0];
        x0 = fmaf(x0, lamL0, F.x);
        x1 = fmaf(x1, lamL1, F.y);
    }

    ushort2* p = reinterpret_cast<ushort2*>(
        up + ((size_t)b * TT + (size_t)c * CLEN) * DST + s0);
    for (int t = 0; t < CLEN; ++t) {
        ushort2 v = p[(size_t)t * (DST / 2)];
        x0 = fmaf(lam0, x0, o0 * bf2f(v.x));
        x1 = fmaf(lam1, x1, o1 * bf2f(v.y));
        p[(size_t)t * (DST / 2)] = make_ushort2(f2bf(x0), f2bf(x1));
    }
}

// ---------------------------------------------------------------------------
extern "C" void kernel_launch(void* const* d_in, const int* in_sizes, int n_in,
                              void* d_out, int out_size, void* d_ws, size_t ws_size,
                              hipStream_t stream)
{
    const float* u     = (const float*)d_in[0];   // B,T,DIN
    const float* W_in  = (const float*)d_in[1];   // DST,DIN
    const float* logl  = (const float*)d_in[2];   // DST
    const float* W_out = (const float*)d_in[3];   // DIN,DST
    const float* Dv    = (const float*)d_in[4];   // DIN
    float* y = (float*)d_out;

    char* ws = (char*)d_ws;
    unsigned short* uA  = (unsigned short*)(ws);                      // 32 MiB
    unsigned short* wA  = (unsigned short*)(ws + (32ull << 20));      //  4 MiB
    unsigned short* wB  = (unsigned short*)(ws + (36ull << 20));      //  4 MiB
    unsigned short* upb = (unsigned short*)(ws + (40ull << 20));      // 64 MiB
    float*          fin = (float*)(ws + (104ull << 20));              //  1 MiB

    // fused fp32 -> bf16 conversions (one launch)
    cvt_all_kernel<<<(N_U4 + 2 * N_W4) / 256, 256, 0, stream>>>(
        u, W_in, W_out, uA, wA, wB);

    // GEMM1: u_proj -> upb bf16, PLUS chunk-finals fin (fused scan1)
    gemm_m97<DIN, DST / 128, false><<<(MM / 128) * (DST / 128), 256, 0, stream>>>(
        uA, wA, upb, nullptr, nullptr, nullptr, logl, fin);

    // scan3 (carry fold inlined): in-place recurrence on upb
    scan3_kernel<<<(BB * CHK * DST / 2) / 256, 256, 0, stream>>>(upb, logl, fin);

    // GEMM2: y = xs @ W_out^T + uA*D   (U read as bf16)
    gemm_m97<DST, DIN / 128, true><<<(MM / 128) * (DIN / 128), 256, 0, stream>>>(
        upb, wB, nullptr, y, uA, Dv, nullptr, nullptr);
}

// Round 13
// 189.471 us; speedup vs baseline: 1.1181x; 1.1181x over previous
//
#include <hip/hip_runtime.h>
#include <math.h>

#define BB   4
#define TT   4096
#define DIN  1024
#define DST  2048
#define MM   (BB*TT)     // 16384
#define CHK  32          // scan chunks per sequence
#define CLEN (TT/CHK)    // 128  (== GEMM1 BM, so M-tile bm <-> chunk bc identity)

typedef __bf16 bf16x8 __attribute__((ext_vector_type(8)));
typedef float  f32x4  __attribute__((ext_vector_type(4)));

__device__ __forceinline__ unsigned short f2bf(float f) {
    union { float f; unsigned u; } v; v.f = f;
    unsigned r = v.u + 0x7FFFu + ((v.u >> 16) & 1u);   // RNE
    return (unsigned short)(r >> 16);
}
__device__ __forceinline__ float bf2f(unsigned short h) {
    union { unsigned u; float f; } v; v.u = ((unsigned)h) << 16;
    return v.f;
}
__device__ __forceinline__ float sigm(float x) { return 1.f / (1.f + __expf(-x)); }

// ---------------------------------------------------------------------------
// fused fp32 -> bf16 conversion of u, W_in, W_out in ONE launch.
// ---------------------------------------------------------------------------
#define N_U4 (MM * DIN / 4)          // 4,194,304
#define N_W4 (DST * DIN / 4)         //   524,288

__global__ __launch_bounds__(256)
void cvt_all_kernel(const float* __restrict__ u,
                    const float* __restrict__ W_in,
                    const float* __restrict__ W_out,
                    unsigned short* __restrict__ uA,
                    unsigned short* __restrict__ wA,
                    unsigned short* __restrict__ wB)
{
    int i = blockIdx.x * 256 + threadIdx.x;
    const float* src; unsigned short* dst; int idx;
    if (i < N_U4)                { src = u;     dst = uA; idx = i; }
    else if (i < N_U4 + N_W4)    { src = W_in;  dst = wA; idx = i - N_U4; }
    else                         { src = W_out; dst = wB; idx = i - N_U4 - N_W4; }
    float4 f = reinterpret_cast<const float4*>(src)[idx];
    ushort4 o;
    o.x = f2bf(f.x); o.y = f2bf(f.y); o.z = f2bf(f.z); o.w = f2bf(f.w);
    reinterpret_cast<ushort4*>(dst)[idx] = o;
}

// ---------------------------------------------------------------------------
// m97-structure bf16 NT MFMA GEMM (886 TF measured R9/R11): 128x128 tile,
// BK=64, 4 waves (2x2), wave tile 64x64, single 32 KiB LDS buffer, 2-barrier
// loop, 16x16x32 MFMA (0-conflict read pattern — 32x32 frag reads cost +4
// cyc/read structurally, R12). XOR swizzle col8 ^= (row&7) both-sides.
// FUSE=false (GEMM1): Obf = bf16(acc); ALSO emits chunk-final
//     fin[bm][s] = sum_t lam_s^{127-t} (1-lam_s) acc[t][s]
// FUSE=true  (GEMM2): Of = acc + bf2f(Ubf)*Dv[col].
// ---------------------------------------------------------------------------
template<int K, int NB, bool FUSE>
__global__ __launch_bounds__(256, 3)
void gemm_m97(const unsigned short* __restrict__ A,
              const unsigned short* __restrict__ B,
              unsigned short* __restrict__ Obf,
              float* __restrict__ Of,
              const unsigned short* __restrict__ Ubf,
              const float* __restrict__ Dv,
              const float* __restrict__ logl,
              float* __restrict__ fin)
{
    constexpr int N  = NB * 128;
    constexpr int NT = K / 64;
    __shared__ __align__(16) unsigned short lds[16384];   // A 16KB + B 16KB

    // XCD-aware bijective swizzle (nwg % 8 == 0: 2048 / 1024 blocks)
    const int nwg = gridDim.x;
    const int bid = blockIdx.x;
    const int swz = (bid & 7) * (nwg >> 3) + (bid >> 3);
    const int bm = swz / NB, bn = swz % NB;

    const int tid  = threadIdx.x;
    const int lane = tid & 63;
    const int wid  = tid >> 6;          // 0..3
    const int wr   = wid >> 1;          // 0..1  (64-row band)
    const int wc   = wid & 1;           // 0..1  (64-col band)
    const int fr   = lane & 15, fq = lane >> 4;

    // --- staging: linear LDS dest, pre-swizzled global source col ---
    const int srow = tid >> 3;                                  // 0..31
    const int scol = (((tid & 7) ^ (srow & 7)) << 3);           // swizzled col
    const unsigned short* Ag = A + (size_t)(bm * 128 + srow) * K + scol;
    const unsigned short* Bg = B + (size_t)(bn * 128 + srow) * K + scol;

    auto stage = [&](int t) {
        const size_t kof = (size_t)t * 64;
#pragma unroll
        for (int r = 0; r < 4; ++r)
            __builtin_amdgcn_global_load_lds(
                (const __attribute__((address_space(1))) void*)(Ag + kof + (size_t)(r * 32) * K),
                (__attribute__((address_space(3))) void*)(&lds[r * 2048 + tid * 8]),
                16, 0, 0);
#pragma unroll
        for (int r = 0; r < 4; ++r)
            __builtin_amdgcn_global_load_lds(
                (const __attribute__((address_space(1))) void*)(Bg + kof + (size_t)(r * 32) * K),
                (__attribute__((address_space(3))) void*)(&lds[8192 + r * 2048 + tid * 8]),
                16, 0, 0);
    };

    // --- frag read addressing (read-side swizzle: row&7 == fr&7) ---
    const int c0 = ((fq ^ (fr & 7)) << 3);          // kk=0 col group
    const int c1 = (((4 + fq) ^ (fr & 7)) << 3);    // kk=1 col group
    const int aBase = (wr * 64 + fr) * 64;                  // + m*1024
    const int bBase = 8192 + (wc * 64 + fr) * 64;           // + n*1024

    f32x4 acc[4][4];
#pragma unroll
    for (int m = 0; m < 4; ++m)
#pragma unroll
        for (int n = 0; n < 4; ++n) {
            acc[m][n][0] = 0.f; acc[m][n][1] = 0.f;
            acc[m][n][2] = 0.f; acc[m][n][3] = 0.f;
        }

    for (int t = 0; t < NT; ++t) {
        __syncthreads();            // all reads of buffer done (prev iter)
        stage(t);
        __syncthreads();            // compiler drains vmcnt before barrier

        bf16x8 af[4], bfv[4];
        // kk = 0
#pragma unroll
        for (int m = 0; m < 4; ++m)
            af[m] = *reinterpret_cast<const bf16x8*>(&lds[aBase + m * 1024 + c0]);
#pragma unroll
        for (int n = 0; n < 4; ++n)
            bfv[n] = *reinterpret_cast<const bf16x8*>(&lds[bBase + n * 1024 + c0]);
#pragma unroll
        for (int m = 0; m < 4; ++m)
#pragma unroll
            for (int n = 0; n < 4; ++n)
                acc[m][n] = __builtin_amdgcn_mfma_f32_16x16x32_bf16(
                    af[m], bfv[n], acc[m][n], 0, 0, 0);
        // kk = 1
#pragma unroll
        for (int m = 0; m < 4; ++m)
            af[m] = *reinterpret_cast<const bf16x8*>(&lds[aBase + m * 1024 + c1]);
#pragma unroll
        for (int n = 0; n < 4; ++n)
            bfv[n] = *reinterpret_cast<const bf16x8*>(&lds[bBase + n * 1024 + c1]);
#pragma unroll
        for (int m = 0; m < 4; ++m)
#pragma unroll
            for (int n = 0; n < 4; ++n)
                acc[m][n] = __builtin_amdgcn_mfma_f32_16x16x32_bf16(
                    af[m], bfv[n], acc[m][n], 0, 0, 0);
    }

    // --- epilogue.  C/D layout: col = lane&15, row = fq*4 + reg ---
    const int row0 = bm * 128 + wr * 64 + fq * 4;
    const int col0 = bn * 128 + wc * 64 + fr;
    if (FUSE) {
#pragma unroll
        for (int n = 0; n < 4; ++n) {
            const int col = col0 + n * 16;
            const float d = Dv[col];
#pragma unroll
            for (int m = 0; m < 4; ++m)
#pragma unroll
                for (int r = 0; r < 4; ++r) {
                    const size_t idx = (size_t)(row0 + m * 16 + r) * N + col;
                    Of[idx] = acc[m][n][r] + bf2f(Ubf[idx]) * d;
                }
        }
    } else {
#pragma unroll
        for (int m = 0; m < 4; ++m)
#pragma unroll
            for (int r = 0; r < 4; ++r) {
                const size_t ro = (size_t)(row0 + m * 16 + r) * N;
#pragma unroll
                for (int n = 0; n < 4; ++n)
                    Obf[ro + col0 + n * 16] = f2bf(acc[m][n][r]);
            }

        // ---- fused scan1: chunk-final F[bm][s] from fp32 acc ----
        // row_local = wr*64 + fq*4 + m*16 + r; weight = lam^(127-row)*(1-lam)
        //           = w0 * li^(m*16+r),  w0 = lam^(127-wr*64-fq*4)*(1-lam)
        float p[4];
#pragma unroll
        for (int n = 0; n < 4; ++n) {
            const int col = bn * 128 + wc * 64 + n * 16 + fr;
            const float lam = sigm(logl[col]);
            const float l2  = log2f(lam);
            const float e0  = (float)(127 - (wr * 64 + fq * 4));
            float w0 = exp2f(e0 * l2) * (1.f - lam);
            const float li  = 1.f / lam;
            const float li2 = li * li, li4 = li2 * li2, li8 = li4 * li4;
            const float li16 = li8 * li8;
            float s = 0.f, wm = w0;
#pragma unroll
            for (int m = 0; m < 4; ++m) {
                float w = wm;
#pragma unroll
                for (int r = 0; r < 4; ++r) {
                    s = fmaf(w, acc[m][n][r], s);
                    w *= li;
                }
                wm *= li16;
            }
            p[n] = s;
        }
        // reduce across fq (lanes ^16, ^32 hold same column)
#pragma unroll
        for (int n = 0; n < 4; ++n) {
            p[n] += __shfl_xor(p[n], 16, 64);
            p[n] += __shfl_xor(p[n], 32, 64);
        }
        __syncthreads();                        // LDS reuse safe
        float* part = reinterpret_cast<float*>(lds);   // [2][128]
        if (fq == 0) {
#pragma unroll
            for (int n = 0; n < 4; ++n)
                part[wr * 128 + wc * 64 + n * 16 + fr] = p[n];
        }
        __syncthreads();
        if (tid < 128)
            fin[(size_t)bm * DST + bn * 128 + tid] = part[tid] + part[128 + tid];
    }
}

// ---------------------------------------------------------------------------
// scan3 (with inlined carry fold): for chunk c, carry = Horner over F[0..c-1],
// then x_t = lam*x_{t-1} + (1-lam)*up_t in place (bf16).
// ---------------------------------------------------------------------------
__global__ __launch_bounds__(256)
void scan3_kernel(unsigned short* __restrict__ up,
                  const float* __restrict__ logl,
                  const float* __restrict__ fin)
{
    const int gid = blockIdx.x * 256 + threadIdx.x;
    const int sp  = gid & (DST / 2 - 1);
    const int bc  = gid >> 10;                         // b*CHK + c
    const int c   = bc & (CHK - 1), b = bc >> 5;
    const int s0  = sp * 2;
    const float lam0 = sigm(logl[s0]),  lam1 = sigm(logl[s0 + 1]);
    const float o0 = 1.f - lam0, o1 = 1.f - lam1;
    float lamL0 = lam0, lamL1 = lam1;
#pragma unroll
    for (int i = 0; i < 7; ++i) { lamL0 *= lamL0; lamL1 *= lamL1; }   // lam^128

    // carry_in = sum_{c'<c} lamL^(c-1-c') * F[c']   (Horner, ascending c')
    float x0 = 0.f, x1 = 0.f;
    for (int cc = 0; cc < c; ++cc) {
        const float2 F = reinterpret_cast<const float2*>(
            fin + (size_t)(b * CHK + cc) * DST + s0)[0];
        x0 = fmaf(x0, lamL0, F.x);
        x1 = fmaf(x1, lamL1, F.y);
    }

    ushort2* p = reinterpret_cast<ushort2*>(
        up + ((size_t)b * TT + (size_t)c * CLEN) * DST + s0);
    for (int t = 0; t < CLEN; ++t) {
        ushort2 v = p[(size_t)t * (DST / 2)];
        x0 = fmaf(lam0, x0, o0 * bf2f(v.x));
        x1 = fmaf(lam1, x1, o1 * bf2f(v.y));
        p[(size_t)t * (DST / 2)] = make_ushort2(f2bf(x0), f2bf(x1));
    }
}

// ---------------------------------------------------------------------------
extern "C" void kernel_launch(void* const* d_in, const int* in_sizes, int n_in,
                              void* d_out, int out_size, void* d_ws, size_t ws_size,
                              hipStream_t stream)
{
    const float* u     = (const float*)d_in[0];   // B,T,DIN
    const float* W_in  = (const float*)d_in[1];   // DST,DIN
    const float* logl  = (const float*)d_in[2];   // DST
    const float* W_out = (const float*)d_in[3];   // DIN,DST
    const float* Dv    = (const float*)d_in[4];   // DIN
    float* y = (float*)d_out;

    char* ws = (char*)d_ws;
    unsigned short* uA  = (unsigned short*)(ws);                      // 32 MiB
    unsigned short* wA  = (unsigned short*)(ws + (32ull << 20));      //  4 MiB
    unsigned short* wB  = (unsigned short*)(ws + (36ull << 20));      //  4 MiB
    unsigned short* upb = (unsigned short*)(ws + (40ull << 20));      // 64 MiB
    float*          fin = (float*)(ws + (104ull << 20));              //  1 MiB

    // fused fp32 -> bf16 conversions (one launch)
    cvt_all_kernel<<<(N_U4 + 2 * N_W4) / 256, 256, 0, stream>>>(
        u, W_in, W_out, uA, wA, wB);

    // GEMM1: u_proj -> upb bf16, PLUS chunk-finals fin (fused scan1)
    gemm_m97<DIN, DST / 128, false><<<(MM / 128) * (DST / 128), 256, 0, stream>>>(
        uA, wA, upb, nullptr, nullptr, nullptr, logl, fin);

    // scan3 (carry fold inlined): in-place recurrence on upb
    scan3_kernel<<<(BB * CHK * DST / 2) / 256, 256, 0, stream>>>(upb, logl, fin);

    // GEMM2: y = xs @ W_out^T + uA*D   (U read as bf16)
    gemm_m97<DST, DIN / 128, true><<<(MM / 128) * (DIN / 128), 256, 0, stream>>>(
        upb, wB, nullptr, y, uA, Dv, nullptr, nullptr);
}